// Round 8
// baseline (128.955 us; speedup 1.0000x reference)
//
#include <hip/hip_runtime.h>
#include <math.h>

// Problem constants (match reference)
constexpr int BN = 128;
constexpr int FH = 26, FW = 26;
constexpr int T  = 50;
constexpr int A  = 5;
constexpr int NC = 20;
constexpr int K  = FH * FW;      // 676
constexpr int KA = K * A;        // 3380
constexpr int CH = A * (5 + NC); // 125

constexpr float IGNORE_THRESH = 0.75f;
constexpr float OBJ_SCALE = 5.0f;
// NOOBJ_SCALE = 1.0 (folded into the math)

constexpr int GCH  = (KA + 255) / 256;   // 14 chunks of 256 slots per batch
constexpr int NBLK = BN * GCH;           // 1792 blocks (= 7/CU * 256 CUs)

__constant__ float ANCW[A] = {1.3221f, 3.19275f, 5.05587f, 9.47112f, 11.2364f};
__constant__ float ANCH[A] = {1.73145f, 4.00944f, 8.09892f, 4.84053f, 10.0071f};

__device__ __forceinline__ float fast_sigmoid(float x) {
    return __builtin_amdgcn_rcpf(1.0f + __expf(-x));
}

// ---------------------------------------------------------------------------
// Single main pass: grid (GCH, BN) = 1792 blocks (28 waves/CU — proven TLP),
// one thread per slot.
//  - 5 pred-plane loads issued BEFORE the decode barriers (latency overlap).
//  - GT decode spread over all 4 waves (t = lane*4 + wave) instead of
//    tid<50 (which serialized all 50 decodes on wave 0).
//  - winner via per-block 256-entry wtab + LDS atomicMax over t (== lax.scan
//    last-valid-wins); IoU loop = ONE ds_read_b128 + ~16 VALU per GT.
//  - pos_any deferred: noobj term unconditional, m>=thresh subset in Mp.
//  - LAST finishing block (device atomicAdd counter, zeroed by a preceding
//    4-byte hipMemsetAsync) reduces all partials L2-hot and stores
//        out = [ sum_b (L_b - any_b * M_b) ] / BN
//    — no separate fix kernel, no extra launch gap.
// ---------------------------------------------------------------------------
__global__ __launch_bounds__(256) void yolo_main(
        const float* __restrict__ outputs,   // (B, 125, 26, 26)
        const float* __restrict__ targets,   // (B, 50, 5)
        float* __restrict__ Lp, float* __restrict__ Mp, int* __restrict__ Anyp,
        unsigned* __restrict__ cnt, float* __restrict__ out) {
    __shared__ float4 sbox[T];    // x1,y1,x2,y2 (degenerate if invalid)
    __shared__ float4 stb[T];     // tb0..tb3
    __shared__ float  scls[T];
    __shared__ int    wtab[256];  // winner t per local slot, -1 if none
    __shared__ float  redl[4], redm[4];
    __shared__ int    reda[4];
    __shared__ int    lastFlag;

    const int b    = blockIdx.y;
    const int tid  = threadIdx.x;
    const int base = blockIdx.x * 256;
    const int s    = base + tid;
    const bool live = s < KA;

    // ---- issue pred loads first (independent of LDS), overlap decode ----
    const int a = live ? (s / K) : 0;
    const int k = live ? (s - a * K) : 0;
    const float* ob = outputs + (size_t)b * CH * K + (size_t)(a * 25) * K;
    float o0 = 0, o1 = 0, o2 = 0, o3 = 0, o4 = 0;
    if (live) {
        o0 = ob[0 * K + k];
        o1 = ob[1 * K + k];
        o2 = ob[2 * K + k];
        o3 = ob[3 * K + k];
        o4 = ob[4 * K + k];
    }

    // ---- phase 1: winner-table init + GT decode (spread over 4 waves) ----
    wtab[tid] = -1;
    const int lane = tid & 63, wv = tid >> 6;
    const int t_own = lane * 4 + wv;          // bijection tid -> t over 0..255
    int myslot = -1;
    if (t_own < T) {
        const float* gt = targets + ((size_t)b * T + t_own) * 5;
        float rx1 = gt[0], ry1 = gt[1], rx2 = gt[2], ry2 = gt[3];
        bool valid = (rx1 + ry1 + rx2 + ry2) > 0.0f;
        float x1 = rx1 * FW, y1 = ry1 * FH, x2 = rx2 * FW, y2 = ry2 * FH;
        float w = x2 - x1, h = y2 - y1;

        float cxf = 0.5f * (x1 + x2), cyf = 0.5f * (y1 + y2);
        int cx = (int)floorf(cxf); cx = min(max(cx, 0), FW - 1);
        int cy = (int)floorf(cyf); cy = min(max(cy, 0), FH - 1);
        int cell = cy * FW + cx;

        // argmax over anchors (strict > => first max wins)
        float acx = (float)cx + 0.5f, acy = (float)cy + 0.5f;
        float best = -1.0f; int ai = 0;
        for (int aa = 0; aa < A; ++aa) {
            float aw = ANCW[aa], ah = ANCH[aa];
            float xi1 = fmaxf(acx - 0.5f * aw, x1), yi1 = fmaxf(acy - 0.5f * ah, y1);
            float xi2 = fminf(acx + 0.5f * aw, x2), yi2 = fminf(acy + 0.5f * ah, y2);
            float inter = fmaxf(xi2 - xi1, 0.0f) * fmaxf(yi2 - yi1, 0.0f);
            float iou = inter / (aw * ah + w * h - inter);
            if (iou > best) { best = iou; ai = aa; }
        }

        sbox[t_own] = valid ? make_float4(x1, y1, x2, y2)
                            : make_float4(1e18f, 1e18f, -1e18f, -1e18f); // inter->0
        stb[t_own]  = make_float4(cxf - (float)cx, cyf - (float)cy,
                                  w / ANCW[ai], h / ANCH[ai]);
        scls[t_own] = gt[4];
        if (valid) myslot = ai * K + cell;
    }
    __syncthreads();

    // ---- phase 2: winner assignment (last valid t wins == atomicMax) ----
    if (myslot >= 0) {
        int local = myslot - base;
        if ((unsigned)local < 256u) atomicMax(&wtab[local], t_own);
    }
    __syncthreads();

    float loss = 0.0f, masked = 0.0f;
    int anyf = 0;

    if (live) {
        const int yy = k / FW, xx = k - yy * FW;
        float s0 = fast_sigmoid(o0), s1 = fast_sigmoid(o1);
        float e2 = __expf(o2),       e3 = __expf(o3);
        float px = (float)xx + s0, py = (float)yy + s1;
        float pw = ANCW[a] * e2,  ph = ANCH[a] * e3;
        float px1 = px - 0.5f * pw, px2 = px + 0.5f * pw;
        float py1 = py - 0.5f * ph, py2 = py + 0.5f * ph;
        float parea = pw * ph;

        float m = -1.0f;
        #pragma unroll 10
        for (int t = 0; t < T; ++t) {
            float4 bx = sbox[t];
            float garea = (bx.z - bx.x) * (bx.w - bx.y);   // ref's a2 expression
            float xi1 = fmaxf(px1, bx.x), yi1 = fmaxf(py1, bx.y);
            float xi2 = fminf(px2, bx.z), yi2 = fminf(py2, bx.w);
            float iw = fmaxf(xi2 - xi1, 0.0f), ih = fmaxf(yi2 - yi1, 0.0f);
            float inter = iw * ih;
            float iou = inter * __builtin_amdgcn_rcpf(parea + garea - inter);
            m = fmaxf(m, iou);
        }
        anyf = (m > IGNORE_THRESH) ? 1 : 0;

        float conf = fast_sigmoid(o4);
        int w = wtab[tid];
        if (w >= 0) {
            // assigned: conf MSE at OBJ scale + box MSE + class CE
            float d = (conf - m) * OBJ_SCALE;
            loss += 0.5f * d * d;
            float4 tb = stb[w];
            float d0 = s0 - tb.x, d1 = s1 - tb.y;
            float d2 = e2 - tb.z, d3 = e3 - tb.w;
            loss += 0.5f * (d0 * d0 + d1 * d1 + d2 * d2 + d3 * d3);

            float v[NC];
            #pragma unroll
            for (int c = 0; c < NC; ++c) v[c] = ob[(5 + c) * K + k];
            float mx = v[0];
            #pragma unroll
            for (int c = 1; c < NC; ++c) mx = fmaxf(mx, v[c]);
            float se = 0.0f;
            #pragma unroll
            for (int c = 0; c < NC; ++c) se += __expf(v[c] - mx);
            int cls = (int)scls[w];
            loss += (__logf(se) + mx) - v[cls];
        } else {
            // unassigned: noobj term (NOOBJ_SCALE=1); cancelled later if pos_any
            float term = 0.5f * conf * conf;
            loss += term;
            if (m >= IGNORE_THRESH) masked += term;
        }
    }

    // ---- block reduce partials ----
    for (int off = 32; off > 0; off >>= 1) {
        loss   += __shfl_down(loss, off);
        masked += __shfl_down(masked, off);
    }
    anyf = __any(anyf) ? 1 : 0;
    if (lane == 0) { redl[wv] = loss; redm[wv] = masked; reda[wv] = anyf; }
    __syncthreads();
    if (tid == 0) {
        int idx = b * GCH + blockIdx.x;
        Lp[idx]   = redl[0] + redl[1] + redl[2] + redl[3];
        Mp[idx]   = redm[0] + redm[1] + redm[2] + redm[3];
        Anyp[idx] = reda[0] | reda[1] | reda[2] | reda[3];
        __threadfence();                       // publish partials device-wide
        unsigned old = atomicAdd(cnt, 1u);     // device-scope
        lastFlag = (old == (unsigned)(NBLK - 1));
    }
    __syncthreads();

    // ---- last finishing block: global reduce + pos_any fix + final store ----
    if (lastFlag) {
        __threadfence();
        float acc = 0.0f;
        if (tid < BN) {
            float L = 0.0f, M = 0.0f;
            int any = 0;
            #pragma unroll
            for (int c = 0; c < GCH; ++c) {
                int idx = tid * GCH + c;
                L += Lp[idx];
                M += Mp[idx];
                any |= Anyp[idx];
            }
            acc = L - (any ? M : 0.0f);
        }
        for (int off = 32; off > 0; off >>= 1) acc += __shfl_down(acc, off);
        if (lane == 0) redl[wv] = acc;
        __syncthreads();
        if (tid == 0)
            out[0] = (redl[0] + redl[1]) * (1.0f / (float)BN);
    }
}

extern "C" void kernel_launch(void* const* d_in, const int* in_sizes, int n_in,
                              void* d_out, int out_size, void* d_ws, size_t ws_size,
                              hipStream_t stream) {
    const float* outputs = (const float*)d_in[0];
    const float* targets = (const float*)d_in[1];
    float* out = (float*)d_out;

    // ws layout: Lp[1792] | Mp[1792] | Anyp[1792] | cnt  (~21 KB)
    float*    Lp   = (float*)d_ws;
    float*    Mp   = Lp + NBLK;
    int*      Anyp = (int*)(Mp + NBLK);
    unsigned* cnt  = (unsigned*)(Anyp + NBLK);

    // zero the completion counter (graph-legal async memset; ws is poisoned
    // 0xAA before every timed launch)
    hipMemsetAsync(cnt, 0, sizeof(unsigned), stream);
    yolo_main<<<dim3(GCH, BN), 256, 0, stream>>>(outputs, targets,
                                                 Lp, Mp, Anyp, cnt, out);
}

// Round 9
// 93.150 us; speedup vs baseline: 1.3844x; 1.3844x over previous
//
#include <hip/hip_runtime.h>
#include <math.h>

// Problem constants (match reference)
constexpr int BN = 128;
constexpr int FH = 26, FW = 26;
constexpr int T  = 50;
constexpr int A  = 5;
constexpr int NC = 20;
constexpr int K  = FH * FW;      // 676
constexpr int KA = K * A;        // 3380
constexpr int CH = A * (5 + NC); // 125

constexpr float IGNORE_THRESH = 0.75f;
constexpr float OBJ_SCALE = 5.0f;
// NOOBJ_SCALE = 1.0 (folded into the math)

constexpr int GCH   = (KA + 255) / 256;   // 14 chunks of 256 slots per batch
constexpr int NPART = BN * GCH;           // 1792 partials

__constant__ float ANCW[A] = {1.3221f, 3.19275f, 5.05587f, 9.47112f, 11.2364f};
__constant__ float ANCH[A] = {1.73145f, 4.00944f, 8.09892f, 4.84053f, 10.0071f};

__device__ __forceinline__ float fast_sigmoid(float x) {
    return __builtin_amdgcn_rcpf(1.0f + __expf(-x));
}

// ---------------------------------------------------------------------------
// Main pass (R7 structure — best measured): grid (GCH, BN) = 1792 blocks
// (28 waves/CU), one thread per slot.
//  - 5 pred-plane loads issued BEFORE the decode barriers (latency overlap).
//  - wave-0 GT decode (tid<50): conflict-free LDS writes (R8's 4-wave spread
//    created 72k bank conflicts via lane*16%32 aliasing — do not respread).
//  - winner via per-block 256-entry wtab + LDS atomicMax over t (== lax.scan
//    last-valid-wins); IoU loop = ONE ds_read_b128 + ~16 VALU per GT.
//  - pos_any deferred: noobj term unconditional, m>=thresh subset in Mp;
//    separate tiny fix kernel (NO in-kernel threadfence/atomic reduce — R8
//    showed per-block __threadfence + hot atomic costs ~35 µs).
//  - partials stored CHUNK-MAJOR (idx = chunk*BN + b) so yolo_fix's folds
//    are coalesced lane-adjacent reads.
// ---------------------------------------------------------------------------
__global__ __launch_bounds__(256) void yolo_main(
        const float* __restrict__ outputs,   // (B, 125, 26, 26)
        const float* __restrict__ targets,   // (B, 50, 5)
        float* __restrict__ Lp, float* __restrict__ Mp, int* __restrict__ Anyp) {
    __shared__ float4 sbox[T];    // x1,y1,x2,y2 (degenerate if invalid)
    __shared__ float4 stb[T];     // tb0..tb3
    __shared__ float  scls[T];
    __shared__ int    wtab[256];  // winner t per local slot, -1 if none
    __shared__ float  redl[4], redm[4];
    __shared__ int    reda[4];

    const int b    = blockIdx.y;
    const int tid  = threadIdx.x;
    const int base = blockIdx.x * 256;
    const int s    = base + tid;
    const bool live = s < KA;

    // ---- issue pred loads first (independent of LDS), overlap decode ----
    const int a = live ? (s / K) : 0;
    const int k = live ? (s - a * K) : 0;
    const float* ob = outputs + (size_t)b * CH * K + (size_t)(a * 25) * K;
    float o0 = 0, o1 = 0, o2 = 0, o3 = 0, o4 = 0;
    if (live) {
        o0 = ob[0 * K + k];
        o1 = ob[1 * K + k];
        o2 = ob[2 * K + k];
        o3 = ob[3 * K + k];
        o4 = ob[4 * K + k];
    }

    // ---- phase 1: winner-table init + GT decode (wave 0) ----
    wtab[tid] = -1;
    int myslot = -1;
    if (tid < T) {
        const float* gt = targets + ((size_t)b * T + tid) * 5;
        float rx1 = gt[0], ry1 = gt[1], rx2 = gt[2], ry2 = gt[3];
        bool valid = (rx1 + ry1 + rx2 + ry2) > 0.0f;
        float x1 = rx1 * FW, y1 = ry1 * FH, x2 = rx2 * FW, y2 = ry2 * FH;
        float w = x2 - x1, h = y2 - y1;

        float cxf = 0.5f * (x1 + x2), cyf = 0.5f * (y1 + y2);
        int cx = (int)floorf(cxf); cx = min(max(cx, 0), FW - 1);
        int cy = (int)floorf(cyf); cy = min(max(cy, 0), FH - 1);
        int cell = cy * FW + cx;

        // argmax over anchors (strict > => first max wins)
        float acx = (float)cx + 0.5f, acy = (float)cy + 0.5f;
        float best = -1.0f; int ai = 0;
        for (int aa = 0; aa < A; ++aa) {
            float aw = ANCW[aa], ah = ANCH[aa];
            float xi1 = fmaxf(acx - 0.5f * aw, x1), yi1 = fmaxf(acy - 0.5f * ah, y1);
            float xi2 = fminf(acx + 0.5f * aw, x2), yi2 = fminf(acy + 0.5f * ah, y2);
            float inter = fmaxf(xi2 - xi1, 0.0f) * fmaxf(yi2 - yi1, 0.0f);
            float iou = inter / (aw * ah + w * h - inter);
            if (iou > best) { best = iou; ai = aa; }
        }

        sbox[tid] = valid ? make_float4(x1, y1, x2, y2)
                          : make_float4(1e18f, 1e18f, -1e18f, -1e18f);  // inter->0
        stb[tid]  = make_float4(cxf - (float)cx, cyf - (float)cy,
                                w / ANCW[ai], h / ANCH[ai]);
        scls[tid] = gt[4];
        if (valid) myslot = ai * K + cell;
    }
    __syncthreads();

    // ---- phase 2: winner assignment (last valid t wins == atomicMax) ----
    if (myslot >= 0) {
        int local = myslot - base;
        if ((unsigned)local < 256u) atomicMax(&wtab[local], tid);
    }
    __syncthreads();

    float loss = 0.0f, masked = 0.0f;
    int anyf = 0;

    if (live) {
        const int yy = k / FW, xx = k - yy * FW;
        float s0 = fast_sigmoid(o0), s1 = fast_sigmoid(o1);
        float e2 = __expf(o2),       e3 = __expf(o3);
        float px = (float)xx + s0, py = (float)yy + s1;
        float pw = ANCW[a] * e2,  ph = ANCH[a] * e3;
        float px1 = px - 0.5f * pw, px2 = px + 0.5f * pw;
        float py1 = py - 0.5f * ph, py2 = py + 0.5f * ph;
        float parea = pw * ph;

        float m = -1.0f;
        #pragma unroll 10
        for (int t = 0; t < T; ++t) {
            float4 bx = sbox[t];
            float garea = (bx.z - bx.x) * (bx.w - bx.y);   // ref's a2 expression
            float xi1 = fmaxf(px1, bx.x), yi1 = fmaxf(py1, bx.y);
            float xi2 = fminf(px2, bx.z), yi2 = fminf(py2, bx.w);
            float iw = fmaxf(xi2 - xi1, 0.0f), ih = fmaxf(yi2 - yi1, 0.0f);
            float inter = iw * ih;
            float iou = inter * __builtin_amdgcn_rcpf(parea + garea - inter);
            m = fmaxf(m, iou);
        }
        anyf = (m > IGNORE_THRESH) ? 1 : 0;

        float conf = fast_sigmoid(o4);
        int w = wtab[tid];
        if (w >= 0) {
            // assigned: conf MSE at OBJ scale + box MSE + class CE
            float d = (conf - m) * OBJ_SCALE;
            loss += 0.5f * d * d;
            float4 tb = stb[w];
            float d0 = s0 - tb.x, d1 = s1 - tb.y;
            float d2 = e2 - tb.z, d3 = e3 - tb.w;
            loss += 0.5f * (d0 * d0 + d1 * d1 + d2 * d2 + d3 * d3);

            float v[NC];
            #pragma unroll
            for (int c = 0; c < NC; ++c) v[c] = ob[(5 + c) * K + k];
            float mx = v[0];
            #pragma unroll
            for (int c = 1; c < NC; ++c) mx = fmaxf(mx, v[c]);
            float se = 0.0f;
            #pragma unroll
            for (int c = 0; c < NC; ++c) se += __expf(v[c] - mx);
            int cls = (int)scls[w];
            loss += (__logf(se) + mx) - v[cls];
        } else {
            // unassigned: noobj term (NOOBJ_SCALE=1); cancelled later if pos_any
            float term = 0.5f * conf * conf;
            loss += term;
            if (m >= IGNORE_THRESH) masked += term;
        }
    }

    // ---- block reduce ----
    for (int off = 32; off > 0; off >>= 1) {
        loss   += __shfl_down(loss, off);
        masked += __shfl_down(masked, off);
    }
    anyf = __any(anyf) ? 1 : 0;
    int lane = tid & 63, wv = tid >> 6;
    if (lane == 0) { redl[wv] = loss; redm[wv] = masked; reda[wv] = anyf; }
    __syncthreads();
    if (tid == 0) {
        int idx = blockIdx.x * BN + b;   // chunk-major: fix reads coalesce
        Lp[idx]   = redl[0] + redl[1] + redl[2] + redl[3];
        Mp[idx]   = redm[0] + redm[1] + redm[2] + redm[3];
        Anyp[idx] = reda[0] | reda[1] | reda[2] | reda[3];
    }
}

// ---------------------------------------------------------------------------
// Fix/reduce: thread b folds its 14 chunk-partials (coalesced: lane-adjacent
// addresses per chunk), applies the pos_any correction, block-reduces 128
// values, single plain store of the scalar.
// ---------------------------------------------------------------------------
__global__ __launch_bounds__(128) void yolo_fix(
        const float* __restrict__ Lp, const float* __restrict__ Mp,
        const int* __restrict__ Anyp, float* __restrict__ out) {
    __shared__ float red[2];
    int tid = threadIdx.x;
    float L = 0.0f, M = 0.0f;
    int any = 0;
    if (tid < BN) {
        #pragma unroll
        for (int c = 0; c < GCH; ++c) {
            int idx = c * BN + tid;      // chunk-major
            L += Lp[idx];
            M += Mp[idx];
            any |= Anyp[idx];
        }
    }
    float acc = L - (any ? M : 0.0f);
    for (int off = 32; off > 0; off >>= 1) acc += __shfl_down(acc, off);
    if ((tid & 63) == 0) red[tid >> 6] = acc;
    __syncthreads();
    if (tid == 0) out[0] = (red[0] + red[1]) * (1.0f / (float)BN);
}

extern "C" void kernel_launch(void* const* d_in, const int* in_sizes, int n_in,
                              void* d_out, int out_size, void* d_ws, size_t ws_size,
                              hipStream_t stream) {
    const float* outputs = (const float*)d_in[0];
    const float* targets = (const float*)d_in[1];
    float* out = (float*)d_out;

    // ws layout: Lp[1792] | Mp[1792] | Anyp[1792]  (~21 KB, written before read)
    float* Lp   = (float*)d_ws;
    float* Mp   = Lp + NPART;
    int*   Anyp = (int*)(Mp + NPART);

    yolo_main<<<dim3(GCH, BN), 256, 0, stream>>>(outputs, targets, Lp, Mp, Anyp);
    yolo_fix<<<1, 128, 0, stream>>>(Lp, Mp, Anyp, out);
}